// Round 2
// baseline (243.040 us; speedup 1.0000x reference)
//
#include <hip/hip_runtime.h>

typedef unsigned long long u64;
typedef unsigned int u32;
typedef unsigned short u16;

#define BATCH 2048
#define DIM   64
#define QSIZE 131072
#define HALFB 1024

#define NSPLIT 64                         // column splits (64 groups of 2048 rows)
#define ROWB   256                        // bytes per interleaved [hi 128B | lo 128B] bf16 row
#define QCMASK ((u32)(QSIZE) * ROWB - 1)  // 32 MiB - 1 (power of two)

typedef __attribute__((ext_vector_type(8)))  short short8;
typedef __attribute__((ext_vector_type(4)))  short short4v;
typedef __attribute__((ext_vector_type(16))) float f32x16;
typedef __attribute__((ext_vector_type(4)))  float f32x4;

__device__ __forceinline__ u16 bf16rn(float f) {
  u32 b = __float_as_uint(f);
  return (u16)((b + 0x7FFFu + ((b >> 16) & 1u)) >> 16);
}
__device__ __forceinline__ float bf16tof(u16 h) {
  return __uint_as_float(((u32)h) << 16);
}

// fp32 queue -> interleaved bf16 hi|lo rows (256 B pitch).
// XCD-aligned producer: physical block p runs on XCD p&7 (round-robin dispatch);
// we remap it to data block b = ((p&7)<<10)|(p>>3) so the rows it WRITES belong
// to the column group that sim blocks on the SAME XCD will read -> qc stays in
// the local L2 (4 MB/XCD = exact fit). q reads are non-temporal so the fp32
// stream doesn't evict the fresh qc lines. Also zeroes the 2048 argmax slots.
__global__ void preconv_kernel(const float* __restrict__ q, char* __restrict__ qc,
                               u64* __restrict__ ws)
{
  int p = blockIdx.x;
  int b = ((p & 7) << 10) | (p >> 3);       // bijective for 8192 blocks
  int i = b * 256 + threadIdx.x;            // float4 id, QSIZE*16 total
  if (i < BATCH) ws[i] = 0;
  int row = i >> 4;
  int c4  = i & 15;
  f32x4 v = __builtin_nontemporal_load(((const f32x4*)q) + i);
  short4v hv, lv;
#pragma unroll
  for (int k = 0; k < 4; ++k) {
    u16 hb = bf16rn(v[k]);
    u16 lb = bf16rn(v[k] - bf16tof(hb));
    hv[k] = (short)hb;
    lv[k] = (short)lb;
  }
  size_t off = (size_t)row * ROWB + c4 * 8;
  *(short4v*)(qc + off)       = hv;   // hi half of row
  *(short4v*)(qc + off + 128) = lv;   // lo half of row
}

// sim = x . q^T via 3-pass bf16 hi/lo MFMA, fused row-argmax.
// Barrier-free main loop: B fragments (16 contiguous bytes of a queue row per
// lane) are loaded directly from global into registers, double-buffered; the
// XCD-local L2 (warmed by preconv) provides the reuse. XCD-aware block remap
// keeps all 16 m-blocks of a column group on one XCD.
__global__ __launch_bounds__(256, 2) void sim_argmax_kernel(
    const float* __restrict__ x, const char* __restrict__ qc,
    u64* __restrict__ ws)
{
  __shared__ u64 table[128 * 32];   // 32 KB, epilogue reduce only

  const int tid  = threadIdx.x;
  const int lane = tid & 63;
  const int wave = tid >> 6;
  const int wm   = wave & 1;    // m-half
  const int wn   = wave >> 1;   // column interleave
  const int l31  = lane & 31;
  const int lh   = lane >> 5;

  // XCD swizzle: hw linear id -> xcd = hw&7; each XCD owns 8 column groups,
  // all 16 m-blocks of a group stay on that XCD's L2. Bijective for 1024 wgs.
  const int hw   = blockIdx.x + (blockIdx.y << 4);
  const int mx   = (hw >> 3) & 15;
  const int ycol = ((hw & 7) << 3) | (hw >> 7);
  const int mblk = mx * 128;
  const int colbase = ycol * (QSIZE / NSPLIT);   // 2048-row slice

  // persistent A fragments: A[m=l31][k=kt*16+lh*8+j]
  short8 ah[2][4], al[2][4];
#pragma unroll
  for (int ms = 0; ms < 2; ++ms) {
    const float* xr = x + (size_t)(mblk + wm * 64 + ms * 32 + l31) * DIM;
#pragma unroll
    for (int kt = 0; kt < 4; ++kt) {
      const float* p = xr + kt * 16 + lh * 8;
      float4 v0 = *(const float4*)(p);
      float4 v1 = *(const float4*)(p + 4);
      float vv[8] = {v0.x, v0.y, v0.z, v0.w, v1.x, v1.y, v1.z, v1.w};
      short8 h, l;
#pragma unroll
      for (int i = 0; i < 8; ++i) {
        u16 hb = bf16rn(vv[i]);
        u16 lb = bf16rn(vv[i] - bf16tof(hb));
        h[i] = (short)hb;
        l[i] = (short)lb;
      }
      ah[ms][kt] = h;
      al[ms][kt] = l;
    }
  }

  float best[2][16];
  u32   bidx[2][16];
#pragma unroll
  for (int ms = 0; ms < 2; ++ms)
#pragma unroll
    for (int r = 0; r < 16; ++r) { best[ms][r] = -3.0e38f; bidx[ms][r] = 0; }

  // per-lane fragment base: row (colbase + wn*32 + l31), k-offset lh*16.
  // kt chunks at immediate offsets +0/32/64/96 (hi) and +128.. (lo).
  u32 off = (u32)((colbase + wn * 32 + l31) * ROWB + lh * 16);
  u32 col = (u32)(colbase + wn * 32 + l31);

  short8 pAh[4], pAl[4], pBh[4], pBl[4];

#define LOADB(BH, BL, OFF) do {                                   \
    const char* p_ = qc + ((OFF) & QCMASK);                       \
    BH[0] = *(const short8*)(p_ +   0);                           \
    BH[1] = *(const short8*)(p_ +  32);                           \
    BH[2] = *(const short8*)(p_ +  64);                           \
    BH[3] = *(const short8*)(p_ +  96);                           \
    BL[0] = *(const short8*)(p_ + 128);                           \
    BL[1] = *(const short8*)(p_ + 160);                           \
    BL[2] = *(const short8*)(p_ + 192);                           \
    BL[3] = *(const short8*)(p_ + 224);                           \
  } while (0)

  // identical accumulation order to the verified kernel: per kt, hh, lh, hl.
#define COMPUTE(BH, BL, COL) do {                                              \
    _Pragma("unroll")                                                          \
    for (int ms = 0; ms < 2; ++ms) {                                           \
      f32x16 acc;                                                              \
      _Pragma("unroll")                                                        \
      for (int r = 0; r < 16; ++r) acc[r] = 0.0f;                              \
      __builtin_amdgcn_s_setprio(1);                                           \
      _Pragma("unroll")                                                        \
      for (int kt = 0; kt < 4; ++kt) {                                         \
        acc = __builtin_amdgcn_mfma_f32_32x32x16_bf16(ah[ms][kt], BH[kt], acc, 0, 0, 0); \
        acc = __builtin_amdgcn_mfma_f32_32x32x16_bf16(al[ms][kt], BH[kt], acc, 0, 0, 0); \
        acc = __builtin_amdgcn_mfma_f32_32x32x16_bf16(ah[ms][kt], BL[kt], acc, 0, 0, 0); \
      }                                                                        \
      __builtin_amdgcn_s_setprio(0);                                           \
      _Pragma("unroll")                                                        \
      for (int r = 0; r < 16; ++r) {                                           \
        if (acc[r] > best[ms][r]) { best[ms][r] = acc[r]; bidx[ms][r] = (COL); } \
      }                                                                        \
    }                                                                          \
  } while (0)

  LOADB(pAh, pAl, off); off += 64 * ROWB;
  // 32 iterations of 32 rows per wave (2048 / 2 waves / 32). Final prefetch
  // overshoots the slice; QCMASK wraps it into valid qc (data unused).
#pragma unroll 1
  for (int i = 0; i < 32; i += 2) {
    LOADB(pBh, pBl, off); off += 64 * ROWB;
    COMPUTE(pAh, pAl, col); col += 64;
    LOADB(pAh, pAl, off); off += 64 * ROWB;
    COMPUTE(pBh, pBl, col); col += 64;
  }

#undef LOADB
#undef COMPUTE

  // block reduce: table[row 0..127][l31 0..31], two wn phases, 128-thread scan
  if (wn == 0) {
#pragma unroll
    for (int ms = 0; ms < 2; ++ms)
#pragma unroll
      for (int r = 0; r < 16; ++r) {
        int row = wm * 64 + ms * 32 + (r & 3) + 8 * (r >> 2) + 4 * lh;
        u32 fb = __float_as_uint(best[ms][r]);
        fb = (fb & 0x80000000u) ? ~fb : (fb | 0x80000000u);
        table[row * 32 + l31] = ((u64)fb << 32) | (u32)(~bidx[ms][r]);
      }
  }
  __syncthreads();
  if (wn == 1) {
#pragma unroll
    for (int ms = 0; ms < 2; ++ms)
#pragma unroll
      for (int r = 0; r < 16; ++r) {
        int row = wm * 64 + ms * 32 + (r & 3) + 8 * (r >> 2) + 4 * lh;
        u32 fb = __float_as_uint(best[ms][r]);
        fb = (fb & 0x80000000u) ? ~fb : (fb | 0x80000000u);
        u64 pk = ((u64)fb << 32) | (u32)(~bidx[ms][r]);
        u64* slot = &table[row * 32 + l31];
        if (pk > *slot) *slot = pk;   // unique writer per slot in this phase
      }
  }
  __syncthreads();
  if (tid < 128) {
    u64 mx64 = 0;
    // rotated scan start per lane: kills the 32-way bank conflict
    // (all lanes at stride 256B hit bank 0 otherwise)
    for (int j0 = 0; j0 < 32; ++j0) {
      int j = (j0 + tid) & 31;
      u64 v = table[tid * 32 + j];
      mx64 = (v > mx64) ? v : mx64;
    }
    atomicMax(&ws[mblk + tid], mx64);
  }
}

// Fused tail: new_queue copy-with-substitution (blocks 0..8191), nn gather +
// ptr (blocks 8192..8703). Runs after sim; overwrites the qconv scratch region.
__global__ void finish_kernel(const float* __restrict__ x, const float* __restrict__ q,
                              const int* __restrict__ ptr_in, const u64* __restrict__ ws,
                              float* __restrict__ nn, float* __restrict__ newq,
                              float* __restrict__ nptr)
{
  int bid = blockIdx.x;
  if (bid < 8192) {
    int i = bid * 256 + threadIdx.x;   // float4 index
    int r = i >> 4;
    int c = i & 15;
    int ptr = *ptr_in;
    u32 off = (u32)(r - ptr) & (QSIZE - 1);
    if (off < HALFB) {
      f32x4 v = __builtin_nontemporal_load(((const f32x4*)x) + (off * 16 + c));
      __builtin_nontemporal_store(v, ((f32x4*)newq) + i);
    } else {
      f32x4 v = __builtin_nontemporal_load(((const f32x4*)q) + i);
      __builtin_nontemporal_store(v, ((f32x4*)newq) + i);
    }
  } else {
    int t = (bid - 8192) * 256 + threadIdx.x;  // 0 .. BATCH*DIM-1
    int b = t >> 6;
    int d = t & 63;
    u32 qidx = ~(u32)(ws[b]);
    nn[t] = q[(size_t)qidx * DIM + d];
    if (t == 0) *nptr = (float)(((*ptr_in) + HALFB) & (QSIZE - 1));
  }
}

extern "C" void kernel_launch(void* const* d_in, const int* in_sizes, int n_in,
                              void* d_out, int out_size, void* d_ws, size_t ws_size,
                              hipStream_t stream)
{
  const float* x   = (const float*)d_in[0];
  const float* qx  = (const float*)d_in[1];
  const int*   ptr = (const int*)d_in[2];

  float* out  = (float*)d_out;
  float* nn   = out;
  float* newq = out + BATCH * DIM;
  float* nptr = out + BATCH * DIM + (size_t)QSIZE * DIM;

  char* qc = (char*)newq;   // 32 MB bf16 hi/lo scratch inside the newq slot
  u64*  ws = (u64*)d_ws;    // 2048 packed (sim, ~idx) slots

  preconv_kernel<<<QSIZE * 16 / 256, 256, 0, stream>>>(qx, qc, ws);

  dim3 grid(BATCH / 128, NSPLIT);
  sim_argmax_kernel<<<grid, 256, 0, stream>>>(x, qc, ws);

  finish_kernel<<<8192 + (BATCH * DIM) / 256, 256, 0, stream>>>(
      x, qx, ptr, ws, nn, newq, nptr);
}

// Round 3
// 208.634 us; speedup vs baseline: 1.1649x; 1.1649x over previous
//
#include <hip/hip_runtime.h>

typedef unsigned long long u64;
typedef unsigned int u32;
typedef unsigned short u16;

#define BATCH 2048
#define DIM   64
#define QSIZE 131072
#define HALFB 1024

#define ROWB   256        // bytes per interleaved [hi|lo] bf16 row (16 chunks of 16B, XOR-swizzled)
#define TILEC  128        // sim-columns (queue rows) per LDS tile
#define TILEB  (TILEC * ROWB)   // 32 KB per buffer
#define NTILE  16         // tiles per block (2048-column slice)

typedef __attribute__((ext_vector_type(8)))  short short8;
typedef __attribute__((ext_vector_type(4)))  short short4v;
typedef __attribute__((ext_vector_type(16))) float f32x16;
typedef __attribute__((ext_vector_type(4)))  float f32x4;

__device__ __forceinline__ u16 bf16rn(float f) {
  u32 b = __float_as_uint(f);
  return (u16)((b + 0x7FFFu + ((b >> 16) & 1u)) >> 16);
}
__device__ __forceinline__ float bf16tof(u16 h) {
  return __uint_as_float(((u32)h) << 16);
}

__device__ __forceinline__ void gload_lds16(const void* g, void* l) {
  __builtin_amdgcn_global_load_lds(
      (__attribute__((address_space(1))) void*)(g),
      (__attribute__((address_space(3))) void*)(l),
      16, 0, 0);
}

// fp32 queue -> interleaved bf16 hi|lo rows (256 B pitch), XOR-swizzled:
// logical 16B-chunk c of row r lands at phys = c ^ (r & 15). The sim kernel
// stages rows LINEARLY via global_load_lds (swizzle preserved) and applies the
// XOR on its ds_read addresses -> reads spread across all 32 LDS banks.
// XCD-aligned producer (block p -> data owned by XCD p&7) + nt loads keep qc
// warm in the local L2. Also zeroes the 2048 argmax slots.
__global__ void preconv_kernel(const float* __restrict__ q, char* __restrict__ qc,
                               u64* __restrict__ ws)
{
  int p = blockIdx.x;
  int b = ((p & 7) << 10) | (p >> 3);       // bijective for 8192 blocks
  int i = b * 256 + threadIdx.x;            // float4 id, QSIZE*16 total
  if (i < BATCH) ws[i] = 0;
  int row = i >> 4;
  int c4  = i & 15;
  f32x4 v = __builtin_nontemporal_load(((const f32x4*)q) + i);
  short4v hv, lv;
#pragma unroll
  for (int k = 0; k < 4; ++k) {
    u16 hb = bf16rn(v[k]);
    u16 lb = bf16rn(v[k] - bf16tof(hb));
    hv[k] = (short)hb;
    lv[k] = (short)lb;
  }
  int chunk = c4 >> 1, half = c4 & 1;
  int ph    = chunk ^ (row & 15);           // hi chunk (logical 0..7)
  int pl    = ph ^ 8;                       // lo chunk (logical 8..15)
  size_t base = (size_t)row * ROWB;
  *(short4v*)(qc + base + ph * 16 + half * 8) = hv;
  *(short4v*)(qc + base + pl * 16 + half * 8) = lv;
}

// sim = x . q^T via 3-pass bf16 hi/lo MFMA, fused row-argmax.
// 2-phase pipelined LDS staging (T3 minimum): STAGE(buf[t+1]) issued BEFORE
// the ds_read+MFMA of buf[t]; one vmcnt-draining __syncthreads per tile ->
// staging latency hides under the ~3072-cycle MFMA phase. Coalesced
// global_load_lds (8 lines/instr) replaces round-2's 32-line divergent loads.
__global__ __launch_bounds__(256, 2) void sim_argmax_kernel(
    const float* __restrict__ x, const char* __restrict__ qc,
    u64* __restrict__ ws)
{
  __shared__ char smem[2 * TILEB];   // 64 KB double buffer; epilogue table aliases

  const int tid  = threadIdx.x;
  const int lane = tid & 63;
  const int wave = tid >> 6;
  const int wm   = wave & 1;    // m-half (64 rows)
  const int wn   = wave >> 1;   // col-half (64 cols)
  const int l31  = lane & 31;
  const int lh   = lane >> 5;

  // XCD swizzle: hw linear id -> xcd = hw&7; each XCD owns 8 column groups,
  // all 16 m-blocks of a group stay on that XCD's L2. Bijective for 1024 wgs.
  const int hw   = blockIdx.x + (blockIdx.y << 4);
  const int mx   = (hw >> 3) & 15;
  const int ycol = ((hw & 7) << 3) | (hw >> 7);
  const int mblk = mx * 128;
  const int colbase = ycol * 2048;            // 2048-row queue slice

  const char* qbase = qc + (size_t)colbase * ROWB;

  // ---- prologue: stage tile 0 into buf0 (overlaps A-fragment build) ----
  {
    const char* src = qbase + wave * 1024 + lane * 16;
    char* dst = smem + wave * 1024;
#pragma unroll
    for (int p = 0; p < 8; ++p) gload_lds16(src + p * 4096, dst + p * 4096);
  }

  // persistent A fragments: A[m = l31][k = kt*16 + lh*8 + j]
  short8 ah[2][4], al[2][4];
#pragma unroll
  for (int ms = 0; ms < 2; ++ms) {
    const float* xr = x + (size_t)(mblk + wm * 64 + ms * 32 + l31) * DIM;
#pragma unroll
    for (int kt = 0; kt < 4; ++kt) {
      const float* p = xr + kt * 16 + lh * 8;
      float4 v0 = *(const float4*)(p);
      float4 v1 = *(const float4*)(p + 4);
      float vv[8] = {v0.x, v0.y, v0.z, v0.w, v1.x, v1.y, v1.z, v1.w};
      short8 h, l;
#pragma unroll
      for (int i = 0; i < 8; ++i) {
        u16 hb = bf16rn(vv[i]);
        u16 lb = bf16rn(vv[i] - bf16tof(hb));
        h[i] = (short)hb;
        l[i] = (short)lb;
      }
      ah[ms][kt] = h;
      al[ms][kt] = l;
    }
  }

  float best[2][16];
  u32   bidx[2][16];
#pragma unroll
  for (int ms = 0; ms < 2; ++ms)
#pragma unroll
    for (int r = 0; r < 16; ++r) { best[ms][r] = -3.0e38f; bidx[ms][r] = 0; }

  __syncthreads();   // drains vmcnt(0): tile 0 staged

#pragma unroll 1
  for (int t = 0; t < NTILE; ++t) {
    const char* cur = smem + (t & 1) * TILEB;

    // stage next tile first (T3: issue STAGE before ds_read+MFMA)
    if (t < NTILE - 1) {
      const char* src = qbase + (size_t)(t + 1) * TILEB + wave * 1024 + lane * 16;
      char* dst = smem + ((t + 1) & 1) * TILEB + wave * 1024;
#pragma unroll
      for (int p = 0; p < 8; ++p) gload_lds16(src + p * 4096, dst + p * 4096);
    }

#pragma unroll
    for (int ns = 0; ns < 2; ++ns) {
      const int brow = wn * 64 + ns * 32 + l31;   // tile-local sim-column
      const int sw   = brow & 15;
      short8 bh[4], bl[4];
#pragma unroll
      for (int kt = 0; kt < 4; ++kt) {
        int ph = (kt * 2 + lh) ^ sw;              // hi chunk, swizzled
        bh[kt] = *(const short8*)(cur + brow * ROWB + (ph << 4));
        bl[kt] = *(const short8*)(cur + brow * ROWB + ((ph ^ 8) << 4));
      }
      const u32 col = (u32)(colbase + t * TILEC + brow);

      // identical accumulation order to the verified kernel: per kt, hh, lh, hl.
#pragma unroll
      for (int ms = 0; ms < 2; ++ms) {
        f32x16 acc;
#pragma unroll
        for (int r = 0; r < 16; ++r) acc[r] = 0.0f;
#pragma unroll
        for (int kt = 0; kt < 4; ++kt) {
          acc = __builtin_amdgcn_mfma_f32_32x32x16_bf16(ah[ms][kt], bh[kt], acc, 0, 0, 0);
          acc = __builtin_amdgcn_mfma_f32_32x32x16_bf16(al[ms][kt], bh[kt], acc, 0, 0, 0);
          acc = __builtin_amdgcn_mfma_f32_32x32x16_bf16(ah[ms][kt], bl[kt], acc, 0, 0, 0);
        }
        // col scans ascending (t asc, ns asc); strict '>' keeps smallest index.
#pragma unroll
        for (int r = 0; r < 16; ++r) {
          if (acc[r] > best[ms][r]) { best[ms][r] = acc[r]; bidx[ms][r] = col; }
        }
      }
    }

    // one barrier per tile: drains vmcnt(0) (next tile staged) and ensures all
    // waves finished reading buf[t&1] before iter t+1 overwrites it.
    __syncthreads();
  }

  // block reduce: table[row 0..127][l31 0..31], two wn phases, 128-thread scan.
  // table aliases the staging buffers (loop's final barrier makes this safe).
  u64* table = (u64*)smem;
  if (wn == 0) {
#pragma unroll
    for (int ms = 0; ms < 2; ++ms)
#pragma unroll
      for (int r = 0; r < 16; ++r) {
        int row = wm * 64 + ms * 32 + (r & 3) + 8 * (r >> 2) + 4 * lh;
        u32 fb = __float_as_uint(best[ms][r]);
        fb = (fb & 0x80000000u) ? ~fb : (fb | 0x80000000u);
        table[row * 32 + l31] = ((u64)fb << 32) | (u32)(~bidx[ms][r]);
      }
  }
  __syncthreads();
  if (wn == 1) {
#pragma unroll
    for (int ms = 0; ms < 2; ++ms)
#pragma unroll
      for (int r = 0; r < 16; ++r) {
        int row = wm * 64 + ms * 32 + (r & 3) + 8 * (r >> 2) + 4 * lh;
        u32 fb = __float_as_uint(best[ms][r]);
        fb = (fb & 0x80000000u) ? ~fb : (fb | 0x80000000u);
        u64 pk = ((u64)fb << 32) | (u32)(~bidx[ms][r]);
        u64* slot = &table[row * 32 + l31];
        if (pk > *slot) *slot = pk;   // unique writer per slot in this phase
      }
  }
  __syncthreads();
  if (tid < 128) {
    u64 mx64 = 0;
    // rotated scan start per lane: avoids the 32-way stride-256B bank conflict
    for (int j0 = 0; j0 < 32; ++j0) {
      int j = (j0 + tid) & 31;
      u64 v = table[tid * 32 + j];
      mx64 = (v > mx64) ? v : mx64;
    }
    atomicMax(&ws[mblk + tid], mx64);
  }
}

// Fused tail: new_queue copy-with-substitution (blocks 0..8191), nn gather +
// ptr (blocks 8192..8703). Runs after sim; overwrites the qconv scratch region.
__global__ void finish_kernel(const float* __restrict__ x, const float* __restrict__ q,
                              const int* __restrict__ ptr_in, const u64* __restrict__ ws,
                              float* __restrict__ nn, float* __restrict__ newq,
                              float* __restrict__ nptr)
{
  int bid = blockIdx.x;
  if (bid < 8192) {
    int i = bid * 256 + threadIdx.x;   // float4 index
    int r = i >> 4;
    int c = i & 15;
    int ptr = *ptr_in;
    u32 off = (u32)(r - ptr) & (QSIZE - 1);
    if (off < HALFB) {
      f32x4 v = __builtin_nontemporal_load(((const f32x4*)x) + (off * 16 + c));
      __builtin_nontemporal_store(v, ((f32x4*)newq) + i);
    } else {
      f32x4 v = __builtin_nontemporal_load(((const f32x4*)q) + i);
      __builtin_nontemporal_store(v, ((f32x4*)newq) + i);
    }
  } else {
    int t = (bid - 8192) * 256 + threadIdx.x;  // 0 .. BATCH*DIM-1
    int b = t >> 6;
    int d = t & 63;
    u32 qidx = ~(u32)(ws[b]);
    nn[t] = q[(size_t)qidx * DIM + d];
    if (t == 0) *nptr = (float)(((*ptr_in) + HALFB) & (QSIZE - 1));
  }
}

extern "C" void kernel_launch(void* const* d_in, const int* in_sizes, int n_in,
                              void* d_out, int out_size, void* d_ws, size_t ws_size,
                              hipStream_t stream)
{
  const float* x   = (const float*)d_in[0];
  const float* qx  = (const float*)d_in[1];
  const int*   ptr = (const int*)d_in[2];

  float* out  = (float*)d_out;
  float* nn   = out;
  float* newq = out + BATCH * DIM;
  float* nptr = out + BATCH * DIM + (size_t)QSIZE * DIM;

  char* qc = (char*)newq;   // 32 MB bf16 scratch inside the newq slot
  u64*  ws = (u64*)d_ws;    // 2048 packed (sim, ~idx) slots

  preconv_kernel<<<QSIZE * 16 / 256, 256, 0, stream>>>(qx, qc, ws);

  dim3 grid(BATCH / 128, 64);
  sim_argmax_kernel<<<grid, 256, 0, stream>>>(x, qc, ws);

  finish_kernel<<<8192 + (BATCH * DIM) / 256, 256, 0, stream>>>(
      x, qx, ptr, ws, nn, newq, nptr);
}